// Round 9
// baseline (144.883 us; speedup 1.0000x reference)
//
#include <hip/hip_runtime.h>
#include <math.h>

#define N_TOK   32768
#define K_CODES 8192
#define E_DIM   32
#define BLK     256
#define NCHUNK  16
#define TPC     32          // code tiles per chunk (8192/16/16)
#define TT      4           // token tiles per wave
#define TAU     2e-4f       // proven in R7
#define RG      4           // flagged tokens per recheck block

// d_out element offsets (float32 buffer)
#define OUT_IDX  1048576
#define OUT_QL   1081344
#define OUT_EL   1081345
// d_out z_q region [0, 1048576) doubles as scratch before finalize overwrites:
#define OUTS_PB2   0         // chunks 8-15 pbest: 262144 f32
#define OUTS_PS2   262144    // chunks 8-15 psec
#define OUTS_PI2   524288    // chunks 8-15 pidx (262144 u16 in 131072 f32)
#define OUTS_FLAGS 655360    // 32768 u32
#define OUTS_FLIST 688128    // 32768 i32
#define OUTS_BCNT  720896    // 128 i32
#define OUTS_BOFF  721024    // 128 i32
#define OUTS_NFLAG 721152    // 1 i32

// ws byte offsets
#define WSB_BPK    0         // 514 tiles * 2048 B
#define WSB_PBEST  1052672   // chunks 0-7 pbest (1 MB; rz/nsq overlay after merge)
#define WSB_PSEC   2101248   // 1 MB
#define WSB_PIDX   3149824   // 512 KB u16
#define WSB_FIDX   3674112   // 128 KB
#define WSB_LPART  3805184   // 2 KB

typedef __attribute__((ext_vector_type(8))) short bf16x8;
typedef __attribute__((ext_vector_type(4))) float f32x4;
typedef __attribute__((ext_vector_type(4))) double f64x4;

__device__ inline unsigned short bf16_rne(float x) {
  unsigned u = __builtin_bit_cast(unsigned, x);
  unsigned r = u + 0x7FFFu + ((u >> 16) & 1u);
  return (unsigned short)(r >> 16);
}
__device__ inline float bf16_to_f32(unsigned short h) {
  return __builtin_bit_cast(float, (unsigned)h << 16);
}

// one thread per code: normalize, bf16 hi/lo split, store MFMA-B-packed
__global__ __launch_bounds__(BLK) void prep_emb_kernel(
    const float* __restrict__ emb, char* __restrict__ Bpk)
{
  const int c = blockIdx.x * BLK + threadIdx.x;
  float z[E_DIM];
  const float4* p = (const float4*)(emb + c * E_DIM);
  float s = 0.f;
#pragma unroll
  for (int q = 0; q < 8; ++q) {
    float4 v = p[q];
    ((float4*)z)[q] = v;
    s += v.x * v.x + v.y * v.y + v.z * v.z + v.w * v.w;
  }
  const float rn = 1.f / sqrtf(s + 1e-12f);
  const int tile = c >> 4, row = c & 15;
#pragma unroll
  for (int g = 0; g < 4; ++g) {
    bf16x8 h8, l8;
#pragma unroll
    for (int j = 0; j < 8; ++j) {
      const float zn = z[g * 8 + j] * rn;
      const unsigned short h = bf16_rne(zn);
      h8[j] = (short)h;
      l8[j] = (short)bf16_rne(zn - bf16_to_f32(h));
    }
    char* base = Bpk + (size_t)tile * 2048 + (size_t)(g * 16 + row) * 16;
    *(bf16x8*)(base) = h8;
    *(bf16x8*)(base + 1024) = l8;
  }
}

// per-code f64 constants for recheck: rz = 1/sqrt(n2+eps), nsq = ||e*rz||^2
__global__ __launch_bounds__(256) void prep64_kernel(
    const float* __restrict__ emb, double* __restrict__ rza,
    double* __restrict__ nsqa)
{
  const int c = blockIdx.x * 256 + threadIdx.x;
  const float4* p = (const float4*)(emb + c * E_DIM);
  float4 v[8];
  double n2 = 0.0;
#pragma unroll
  for (int q = 0; q < 8; ++q) {
    v[q] = p[q];
    const double ex = v[q].x, ey = v[q].y, ez = v[q].z, ew = v[q].w;
    n2 = fma(ew, ew, fma(ez, ez, fma(ey, ey, fma(ex, ex, n2))));
  }
  const double rz = 1.0 / sqrt(n2 + 1e-12);
  double nsq = 0.0;
#pragma unroll
  for (int q = 0; q < 8; ++q) {
    const double ex = (double)v[q].x * rz, ey = (double)v[q].y * rz;
    const double ez = (double)v[q].z * rz, ew = (double)v[q].w * rz;
    nsq = fma(ew, ew, fma(ez, ez, fma(ey, ey, fma(ex, ex, nsq))));
  }
  rza[c] = rz;
  nsqa[c] = nsq;
}

// grid: 2048 blocks (chunk = bid>>7 in 0..15, token-block = bid&127).
// 16 K-chunks offer 8 waves/SIMD (matches the 64-VGPR capacity tier);
// per-chunk scores are bit-identical to the 8-chunk partitioning.
__global__ __launch_bounds__(BLK, 4) void screen_kernel(
    const float* __restrict__ hs, const char* __restrict__ Bpk,
    float* __restrict__ pb1, float* __restrict__ ps1, unsigned short* __restrict__ pi1,
    float* __restrict__ pb2, float* __restrict__ ps2, unsigned short* __restrict__ pi2)
{
  const int lane = threadIdx.x & 63;
  const int wave = threadIdx.x >> 6;
  const int grp = lane >> 4, row = lane & 15;
  const int chunk = blockIdx.x >> 7;
  const int tb = blockIdx.x & 127;
  const int tile0 = tb * 16 + wave * TT;

  bf16x8 ahi[TT], alo[TT];
#pragma unroll
  for (int tt = 0; tt < TT; ++tt) {
    const float* ap = hs + ((tile0 + tt) * 16 + row) * E_DIM + grp * 8;
    float a[8];
    ((float4*)a)[0] = ((const float4*)ap)[0];
    ((float4*)a)[1] = ((const float4*)ap)[1];
    float ps = 0.f;
#pragma unroll
    for (int j = 0; j < 8; ++j) ps = fmaf(a[j], a[j], ps);
    ps += __shfl_xor(ps, 16, 64);
    ps += __shfl_xor(ps, 32, 64);
    const float rn = 1.f / sqrtf(ps + 1e-12f);
#pragma unroll
    for (int j = 0; j < 8; ++j) {
      const float zn = a[j] * rn;
      const unsigned short h = bf16_rne(zn);
      ahi[tt][j] = (short)h;
      alo[tt][j] = (short)bf16_rne(zn - bf16_to_f32(h));
    }
  }

  float best[TT][4], sec[TT][4];
  int bct[TT][4];
#pragma unroll
  for (int tt = 0; tt < TT; ++tt)
#pragma unroll
    for (int r = 0; r < 4; ++r) { best[tt][r] = -3e38f; sec[tt][r] = -3e38f; bct[tt][r] = 0; }

  const f32x4 Z4 = {0.f, 0.f, 0.f, 0.f};
  const char* Bc = Bpk + (size_t)(chunk * TPC) * 2048 + (size_t)lane * 16;

#define PROC(CH, CL, CTV)                                                      \
  {                                                                            \
    f32x4 acc[TT];                                                             \
    _Pragma("unroll") for (int tt = 0; tt < TT; ++tt) {                        \
      acc[tt] = __builtin_amdgcn_mfma_f32_16x16x32_bf16(ahi[tt], (CH), Z4, 0, 0, 0); \
      acc[tt] = __builtin_amdgcn_mfma_f32_16x16x32_bf16(ahi[tt], (CL), acc[tt], 0, 0, 0); \
      acc[tt] = __builtin_amdgcn_mfma_f32_16x16x32_bf16(alo[tt], (CH), acc[tt], 0, 0, 0); \
    }                                                                          \
    _Pragma("unroll") for (int tt = 0; tt < TT; ++tt)                          \
    _Pragma("unroll") for (int r = 0; r < 4; ++r) {                            \
      const float d = acc[tt][r];                                              \
      sec[tt][r] = __builtin_amdgcn_fmed3f(best[tt][r], sec[tt][r], d);        \
      if (d > best[tt][r]) { best[tt][r] = d; bct[tt][r] = (CTV); }            \
    }                                                                          \
  }

  bf16x8 h0 = *(const bf16x8*)(Bc);
  bf16x8 l0 = *(const bf16x8*)(Bc + 1024);
  bf16x8 h1 = *(const bf16x8*)(Bc + 2048);
  bf16x8 l1 = *(const bf16x8*)(Bc + 3072);
  for (int ct = 0; ct < TPC; ct += 2) {
    const bf16x8 ch0 = h0, cl0 = l0, ch1 = h1, cl1 = l1;
    const char* pn = Bc + (size_t)(ct + 2) * 2048;   // pad tiles keep this safe
    h0 = *(const bf16x8*)(pn);
    l0 = *(const bf16x8*)(pn + 1024);
    h1 = *(const bf16x8*)(pn + 2048);
    l1 = *(const bf16x8*)(pn + 3072);
    PROC(ch0, cl0, ct)
    PROC(ch1, cl1, ct + 1)
  }
#undef PROC

  float* __restrict__ pbest = (chunk < 8) ? pb1 : pb2;
  float* __restrict__ psec  = (chunk < 8) ? ps1 : ps2;
  unsigned short* __restrict__ pidx = (chunk < 8) ? pi1 : pi2;
  const int base = (chunk & 7) * N_TOK;
#pragma unroll
  for (int tt = 0; tt < TT; ++tt) {
#pragma unroll
    for (int r = 0; r < 4; ++r) {
      float b = best[tt][r], s = sec[tt][r];
      int id = bct[tt][r] * 16 + row;   // code within chunk [0,512)
#pragma unroll
      for (int w = 1; w < 16; w <<= 1) {
        const float ob = __shfl_xor(b, w, 64);
        const float os = __shfl_xor(s, w, 64);
        const int   oi = __shfl_xor(id, w, 64);
        s = fmaxf(fmaxf(s, os), fminf(b, ob));
        if (ob > b || (ob == b && oi < id)) id = oi;
        b = fmaxf(b, ob);
      }
      if (row == 0) {
        const int tok = (tile0 + tt) * 16 + grp * 4 + r;
        pbest[base + tok] = b;
        psec[base + tok] = s;
        pidx[base + tok] = (unsigned short)(chunk * 512 + id);
      }
    }
  }
}

// merge 16 chunk-partials; write per-token flag (no atomics) + per-block count
__global__ __launch_bounds__(BLK) void merge_kernel(
    const float* __restrict__ pb1, const float* __restrict__ ps1,
    const unsigned short* __restrict__ pi1,
    const float* __restrict__ pb2, const float* __restrict__ ps2,
    const unsigned short* __restrict__ pi2,
    int* __restrict__ fidx, unsigned* __restrict__ flags,
    int* __restrict__ bcount)
{
  const int t = blockIdx.x * BLK + threadIdx.x;
  float best = -3e38f, sec = -3e38f;
  int code = 0;
#pragma unroll
  for (int ch = 0; ch < NCHUNK; ++ch) {
    const int o = (ch & 7) * N_TOK + t;
    const float b = (ch < 8) ? pb1[o] : pb2[o];
    const float s = (ch < 8) ? ps1[o] : ps2[o];
    const int c = (ch < 8) ? pi1[o] : pi2[o];
    if (b > best) { sec = fmaxf(best, s); best = b; code = c; }
    else          { sec = fmaxf(sec, b); }
  }
  fidx[t] = code;
  const unsigned f = (best - sec < TAU) ? 1u : 0u;
  flags[t] = f;
  // deterministic per-block flag count
  __shared__ int wcnt[4];
  const unsigned long long m = __ballot(f != 0);
  if ((threadIdx.x & 63) == 0) wcnt[threadIdx.x >> 6] = (int)__popcll(m);
  __syncthreads();
  if (threadIdx.x == 0)
    bcount[blockIdx.x] = wcnt[0] + wcnt[1] + wcnt[2] + wcnt[3];
}

// exclusive scan of 128 block counts (1 block, deterministic)
__global__ __launch_bounds__(128) void scan_kernel(
    const int* __restrict__ bcount, int* __restrict__ boff,
    int* __restrict__ nflagp)
{
  __shared__ int sh[128];
  const int tid = threadIdx.x;
  const int c = bcount[tid];
  sh[tid] = c;
  __syncthreads();
#pragma unroll
  for (int off = 1; off < 128; off <<= 1) {
    int v = 0;
    if (tid >= off) v = sh[tid - off];
    __syncthreads();
    sh[tid] += v;
    __syncthreads();
  }
  boff[tid] = sh[tid] - c;
  if (tid == 127) *nflagp = sh[127];
}

// deterministic compaction: flagged tokens in ascending order
__global__ __launch_bounds__(BLK) void scatter_kernel(
    const unsigned* __restrict__ flags, const int* __restrict__ boff,
    int* __restrict__ flaglist)
{
  const int tid = threadIdx.x;
  const int t = blockIdx.x * BLK + tid;
  const unsigned f = flags[t];
  const int lane = tid & 63, wv = tid >> 6;
  const unsigned long long m = __ballot(f != 0);
  __shared__ int wtot[4], woff[4];
  if (lane == 0) wtot[wv] = (int)__popcll(m);
  __syncthreads();
  if (tid == 0) {
    int s = 0;
#pragma unroll
    for (int w = 0; w < 4; ++w) { woff[w] = s; s += wtot[w]; }
  }
  __syncthreads();
  if (f) {
    const int rank = (int)__popcll(m & ((1ull << lane) - 1ull));
    flaglist[boff[blockIdx.x] + woff[wv] + rank] = t;
  }
}

// exact f64 rescan for flagged tokens, RG tokens per block (R7-proven body)
__global__ __launch_bounds__(256, 1) void recheck_kernel(
    const float* __restrict__ hs, const float* __restrict__ emb,
    const double* __restrict__ rza, const double* __restrict__ nsqa,
    const int* __restrict__ nflagp, const int* __restrict__ flaglist,
    int* __restrict__ fidx)
{
  __shared__ __align__(16) double zsh[RG][E_DIM];
  __shared__ int tsh[RG];
  __shared__ double rvW[RG][4];
  __shared__ int riW[RG][4];
  const int tid = threadIdx.x;
  const int lane = tid & 63, wv = tid >> 6;
  const int nflag = *nflagp;
  for (int base = blockIdx.x * RG; base < nflag; base += gridDim.x * RG) {
    __syncthreads();   // previous iteration's zsh/tsh/rvW consumers are done
    if (tid < 128) {
      const int g = tid >> 5, j = tid & 31;
      const bool act = (base + g) < nflag;
      const int t = act ? flaglist[base + g] : -1;
      if (j == 0) tsh[g] = t;
      const double zj = act ? (double)hs[t * E_DIM + j] : 0.0;
      double sq = zj * zj;
#pragma unroll
      for (int o = 16; o > 0; o >>= 1) sq += __shfl_xor(sq, o, 32);
      const double rzt = 1.0 / sqrt(sq + 1e-12);
      zsh[g][j] = zj * rzt;
    }
    __syncthreads();

    double bobj[RG];
    int bidx[RG];
#pragma unroll
    for (int g = 0; g < RG; ++g) { bobj[g] = 1e300; bidx[g] = 0x7fffffff; }

    for (int c = tid; c < K_CODES; c += 256) {
      const float4* ep = (const float4*)(emb + c * E_DIM);
      f64x4 e64[8];
#pragma unroll
      for (int q = 0; q < 8; ++q) {
        const float4 v = ep[q];
        e64[q][0] = (double)v.x; e64[q][1] = (double)v.y;
        e64[q][2] = (double)v.z; e64[q][3] = (double)v.w;
      }
      const double rzc = rza[c], nsqc = nsqa[c];
#pragma unroll
      for (int g = 0; g < RG; ++g) {
        double d0 = 0.0, d1 = 0.0;
#pragma unroll
        for (int q = 0; q < 8; q += 2) {
#pragma unroll
          for (int x = 0; x < 4; ++x) {
            d0 = fma(e64[q][x],     zsh[g][q * 4 + x],       d0);
            d1 = fma(e64[q + 1][x], zsh[g][(q + 1) * 4 + x], d1);
          }
        }
        const double obj = fma(-2.0, (d0 + d1) * rzc, nsqc);
        if (obj < bobj[g]) { bobj[g] = obj; bidx[g] = c; }
      }
    }

#pragma unroll
    for (int g = 0; g < RG; ++g) {
      double b = bobj[g]; int i = bidx[g];
#pragma unroll
      for (int o = 32; o > 0; o >>= 1) {
        const double ob = __shfl_down(b, o, 64);
        const int oi = __shfl_down(i, o, 64);
        if (ob < b || (ob == b && oi < i)) { b = ob; i = oi; }
      }
      if (lane == 0) { rvW[g][wv] = b; riW[g][wv] = i; }
    }
    __syncthreads();
    if (tid < RG) {
      const int g = tid;
      double b = rvW[g][0]; int i = riW[g][0];
#pragma unroll
      for (int w = 1; w < 4; ++w) {
        const double ob = rvW[g][w]; const int oi = riW[g][w];
        if (ob < b || (ob == b && oi < i)) { b = ob; i = oi; }
      }
      const int t = tsh[g];
      if (t >= 0) fidx[t] = i;
    }
  }
}

__global__ __launch_bounds__(BLK) void finalize_kernel(
    const float* __restrict__ hs, const float* __restrict__ emb,
    const int* __restrict__ fidx, float* __restrict__ out,
    float* __restrict__ lpart)
{
  const int t = blockIdx.x * BLK + threadIdx.x;
  const int idx = fidx[t];
  const float4* ep = (const float4*)(emb + idx * E_DIM);
  const float4* hp = (const float4*)(hs + t * E_DIM);
  float4 e[8], h[8];
  float se = 0.f, sh = 0.f;
#pragma unroll
  for (int q = 0; q < 8; ++q) {
    e[q] = ep[q]; h[q] = hp[q];
    se += e[q].x * e[q].x + e[q].y * e[q].y + e[q].z * e[q].z + e[q].w * e[q].w;
    sh += h[q].x * h[q].x + h[q].y * h[q].y + h[q].z * h[q].z + h[q].w * h[q].w;
  }
  const float re = 1.f / sqrtf(se + 1e-12f);
  const float rh = 1.f / sqrtf(sh + 1e-12f);
  float4* zo = (float4*)(out + t * E_DIM);
  float err = 0.f;
#pragma unroll
  for (int q = 0; q < 8; ++q) {
    float4 zq, hn;
    zq.x = e[q].x * re; zq.y = e[q].y * re; zq.z = e[q].z * re; zq.w = e[q].w * re;
    hn.x = h[q].x * rh; hn.y = h[q].y * rh; hn.z = h[q].z * rh; hn.w = h[q].w * rh;
    float dx = zq.x - hn.x, dy = zq.y - hn.y, dz = zq.z - hn.z, dw = zq.w - hn.w;
    err += dx * dx + dy * dy + dz * dz + dw * dw;
    zo[q] = zq;
  }
  out[OUT_IDX + t] = (float)idx;
#pragma unroll
  for (int o = 32; o > 0; o >>= 1) err += __shfl_down(err, o);
  if ((threadIdx.x & 63) == 0) lpart[t >> 6] = err;
}

__global__ __launch_bounds__(256) void loss_kernel(
    const float* __restrict__ lpart, float* __restrict__ out)
{
  const int tid = threadIdx.x;
  float a = lpart[tid] + lpart[tid + 256];
#pragma unroll
  for (int o = 32; o > 0; o >>= 1) a += __shfl_down(a, o);
  __shared__ float w[4];
  if ((tid & 63) == 0) w[tid >> 6] = a;
  __syncthreads();
  if (tid == 0) {
    const float tot = (w[0] + w[1]) + (w[2] + w[3]);
    const float c = tot * (1.0f / 1048576.0f);
    out[OUT_QL] = c;
    out[OUT_EL] = c;
  }
}

extern "C" void kernel_launch(void* const* d_in, const int* in_sizes, int n_in,
                              void* d_out, int out_size, void* d_ws, size_t ws_size,
                              hipStream_t stream) {
  (void)in_sizes; (void)n_in; (void)out_size; (void)ws_size;
  const float* hs  = (const float*)d_in[0];
  const float* emb = (const float*)d_in[1];
  float* out = (float*)d_out;
  char* wsb = (char*)d_ws;

  char*           Bpk   = wsb + WSB_BPK;
  float*          pb1   = (float*)(wsb + WSB_PBEST);
  float*          ps1   = (float*)(wsb + WSB_PSEC);
  unsigned short* pi1   = (unsigned short*)(wsb + WSB_PIDX);
  int*            fidx  = (int*)(wsb + WSB_FIDX);
  float*          lpart = (float*)(wsb + WSB_LPART);
  double*         rza   = (double*)(wsb + WSB_PBEST);          // overlay, after merge
  double*         nsqa  = (double*)(wsb + WSB_PBEST + 65536);
  // out z_q region as pre-finalize scratch (fully overwritten by finalize)
  float*          pb2     = out + OUTS_PB2;
  float*          ps2     = out + OUTS_PS2;
  unsigned short* pi2     = (unsigned short*)(out + OUTS_PI2);
  unsigned*       flags   = (unsigned*)(out + OUTS_FLAGS);
  int*            flist   = (int*)(out + OUTS_FLIST);
  int*            bcount  = (int*)(out + OUTS_BCNT);
  int*            boff    = (int*)(out + OUTS_BOFF);
  int*            nflagp  = (int*)(out + OUTS_NFLAG);

  prep_emb_kernel<<<dim3(K_CODES / BLK), BLK, 0, stream>>>(emb, Bpk);
  screen_kernel<<<dim3(NCHUNK * 128), BLK, 0, stream>>>(hs, Bpk, pb1, ps1, pi1, pb2, ps2, pi2);
  merge_kernel<<<dim3(N_TOK / BLK), BLK, 0, stream>>>(pb1, ps1, pi1, pb2, ps2, pi2, fidx, flags, bcount);
  scan_kernel<<<dim3(1), 128, 0, stream>>>(bcount, boff, nflagp);
  scatter_kernel<<<dim3(N_TOK / BLK), BLK, 0, stream>>>(flags, boff, flist);
  prep64_kernel<<<dim3(K_CODES / 256), 256, 0, stream>>>(emb, rza, nsqa);
  recheck_kernel<<<dim3(512), 256, 0, stream>>>(hs, emb, rza, nsqa, nflagp, flist, fidx);
  finalize_kernel<<<dim3(N_TOK / BLK), BLK, 0, stream>>>(hs, emb, fidx, out, lpart);
  loss_kernel<<<dim3(1), 256, 0, stream>>>(lpart, out);
}

// Round 10
// 135.316 us; speedup vs baseline: 1.0707x; 1.0707x over previous
//
#include <hip/hip_runtime.h>
#include <math.h>

#define N_TOK   32768
#define K_CODES 8192
#define E_DIM   32
#define BLK     256
#define NCHUNK  8
#define TPC     64          // code tiles per chunk (8192/8/16)
#define TT      4           // token tiles per wave
#define TAU     2e-4f       // proven in R7
#define RG      4           // flagged tokens per recheck block

// d_out element offsets (float32 buffer)
#define OUT_IDX  1048576
#define OUT_QL   1081344
#define OUT_EL   1081345
// d_out z_q region [0, 1048576) doubles as scratch before finalize overwrites:
#define OUTS_FLAGS 655360    // 32768 u32
#define OUTS_FLIST 688128    // 32768 i32
#define OUTS_BCNT  720896    // 128 i32
#define OUTS_BOFF  721024    // 128 i32
#define OUTS_NFLAG 721152    // 1 i32

// ws byte offsets
#define WSB_BPK    0         // 514 tiles * 2048 B
#define WSB_PBEST  1052672   // 8*32768 f32 (rz/nsq overlay after merge)
#define WSB_PSEC   2101248   // 1 MB
#define WSB_PIDX   3149824   // 512 KB u16
#define WSB_FIDX   3674112   // 128 KB
#define WSB_LPART  3805184   // 2 KB

typedef __attribute__((ext_vector_type(8))) short bf16x8;
typedef __attribute__((ext_vector_type(4))) float f32x4;
typedef __attribute__((ext_vector_type(4))) double f64x4;

__device__ inline unsigned short bf16_rne(float x) {
  unsigned u = __builtin_bit_cast(unsigned, x);
  unsigned r = u + 0x7FFFu + ((u >> 16) & 1u);
  return (unsigned short)(r >> 16);
}
__device__ inline float bf16_to_f32(unsigned short h) {
  return __builtin_bit_cast(float, (unsigned)h << 16);
}

// one thread per code: normalize, bf16 hi/lo split, store MFMA-B-packed
__global__ __launch_bounds__(BLK) void prep_emb_kernel(
    const float* __restrict__ emb, char* __restrict__ Bpk)
{
  const int c = blockIdx.x * BLK + threadIdx.x;
  float z[E_DIM];
  const float4* p = (const float4*)(emb + c * E_DIM);
  float s = 0.f;
#pragma unroll
  for (int q = 0; q < 8; ++q) {
    float4 v = p[q];
    ((float4*)z)[q] = v;
    s += v.x * v.x + v.y * v.y + v.z * v.z + v.w * v.w;
  }
  const float rn = 1.f / sqrtf(s + 1e-12f);
  const int tile = c >> 4, row = c & 15;
#pragma unroll
  for (int g = 0; g < 4; ++g) {
    bf16x8 h8, l8;
#pragma unroll
    for (int j = 0; j < 8; ++j) {
      const float zn = z[g * 8 + j] * rn;
      const unsigned short h = bf16_rne(zn);
      h8[j] = (short)h;
      l8[j] = (short)bf16_rne(zn - bf16_to_f32(h));
    }
    char* base = Bpk + (size_t)tile * 2048 + (size_t)(g * 16 + row) * 16;
    *(bf16x8*)(base) = h8;
    *(bf16x8*)(base + 1024) = l8;
  }
}

// per-code f64 constants for recheck: rz = 1/sqrt(n2+eps), nsq = ||e*rz||^2
__global__ __launch_bounds__(256) void prep64_kernel(
    const float* __restrict__ emb, double* __restrict__ rza,
    double* __restrict__ nsqa)
{
  const int c = blockIdx.x * 256 + threadIdx.x;
  const float4* p = (const float4*)(emb + c * E_DIM);
  float4 v[8];
  double n2 = 0.0;
#pragma unroll
  for (int q = 0; q < 8; ++q) {
    v[q] = p[q];
    const double ex = v[q].x, ey = v[q].y, ez = v[q].z, ew = v[q].w;
    n2 = fma(ew, ew, fma(ez, ez, fma(ey, ey, fma(ex, ex, n2))));
  }
  const double rz = 1.0 / sqrt(n2 + 1e-12);
  double nsq = 0.0;
#pragma unroll
  for (int q = 0; q < 8; ++q) {
    const double ex = (double)v[q].x * rz, ey = (double)v[q].y * rz;
    const double ez = (double)v[q].z * rz, ew = (double)v[q].w * rz;
    nsq = fma(ew, ew, fma(ez, ez, fma(ey, ey, fma(ex, ex, nsq))));
  }
  rza[c] = rz;
  nsqa[c] = nsq;
}

// grid: 1024 blocks (chunk = bid>>7, token-block = bid&127), 256 thr = 4 waves.
// amdgpu_waves_per_eu(4,4): pin the scheduler's occupancy TARGET to 4 waves/EU
// (128-VGPR tier) so the ~120 live regs fit without spilling. launch_bounds'
// 2nd arg only caps the budget; R7(,4)/R8(,2) both still chose the 64-VGPR/
// 8-wave tier and spilled ~60 regs -> 74-80 us. Grid supplies exactly 4/SIMD.
__global__ __launch_bounds__(BLK)
__attribute__((amdgpu_waves_per_eu(4, 4)))
void screen_kernel(
    const float* __restrict__ hs, const char* __restrict__ Bpk,
    float* __restrict__ pbest, float* __restrict__ psec,
    unsigned short* __restrict__ pidx)
{
  const int lane = threadIdx.x & 63;
  const int wave = threadIdx.x >> 6;
  const int grp = lane >> 4, row = lane & 15;
  const int chunk = blockIdx.x >> 7;
  const int tb = blockIdx.x & 127;
  const int tile0 = tb * 16 + wave * TT;

  bf16x8 ahi[TT], alo[TT];
#pragma unroll
  for (int tt = 0; tt < TT; ++tt) {
    const float* ap = hs + ((tile0 + tt) * 16 + row) * E_DIM + grp * 8;
    float a[8];
    ((float4*)a)[0] = ((const float4*)ap)[0];
    ((float4*)a)[1] = ((const float4*)ap)[1];
    float ps = 0.f;
#pragma unroll
    for (int j = 0; j < 8; ++j) ps = fmaf(a[j], a[j], ps);
    ps += __shfl_xor(ps, 16, 64);
    ps += __shfl_xor(ps, 32, 64);
    const float rn = 1.f / sqrtf(ps + 1e-12f);
#pragma unroll
    for (int j = 0; j < 8; ++j) {
      const float zn = a[j] * rn;
      const unsigned short h = bf16_rne(zn);
      ahi[tt][j] = (short)h;
      alo[tt][j] = (short)bf16_rne(zn - bf16_to_f32(h));
    }
  }

  float best[TT][4], sec[TT][4];
  int bct[TT][4];
#pragma unroll
  for (int tt = 0; tt < TT; ++tt)
#pragma unroll
    for (int r = 0; r < 4; ++r) { best[tt][r] = -3e38f; sec[tt][r] = -3e38f; bct[tt][r] = 0; }

  const f32x4 Z4 = {0.f, 0.f, 0.f, 0.f};
  const char* Bc = Bpk + (size_t)(chunk * TPC) * 2048 + (size_t)lane * 16;

#define PROC(CH, CL, CTV)                                                      \
  {                                                                            \
    f32x4 acc[TT];                                                             \
    _Pragma("unroll") for (int tt = 0; tt < TT; ++tt) {                        \
      acc[tt] = __builtin_amdgcn_mfma_f32_16x16x32_bf16(ahi[tt], (CH), Z4, 0, 0, 0); \
      acc[tt] = __builtin_amdgcn_mfma_f32_16x16x32_bf16(ahi[tt], (CL), acc[tt], 0, 0, 0); \
      acc[tt] = __builtin_amdgcn_mfma_f32_16x16x32_bf16(alo[tt], (CH), acc[tt], 0, 0, 0); \
    }                                                                          \
    _Pragma("unroll") for (int tt = 0; tt < TT; ++tt)                          \
    _Pragma("unroll") for (int r = 0; r < 4; ++r) {                            \
      const float d = acc[tt][r];                                              \
      sec[tt][r] = __builtin_amdgcn_fmed3f(best[tt][r], sec[tt][r], d);        \
      if (d > best[tt][r]) { best[tt][r] = d; bct[tt][r] = (CTV); }            \
    }                                                                          \
  }

  bf16x8 h0 = *(const bf16x8*)(Bc);
  bf16x8 l0 = *(const bf16x8*)(Bc + 1024);
  bf16x8 h1 = *(const bf16x8*)(Bc + 2048);
  bf16x8 l1 = *(const bf16x8*)(Bc + 3072);
  for (int ct = 0; ct < TPC; ct += 2) {
    const bf16x8 ch0 = h0, cl0 = l0, ch1 = h1, cl1 = l1;
    const char* pn = Bc + (size_t)(ct + 2) * 2048;   // pad tiles keep this safe
    h0 = *(const bf16x8*)(pn);
    l0 = *(const bf16x8*)(pn + 1024);
    h1 = *(const bf16x8*)(pn + 2048);
    l1 = *(const bf16x8*)(pn + 3072);
    PROC(ch0, cl0, ct)
    PROC(ch1, cl1, ct + 1)
  }
#undef PROC

  const int base = chunk * N_TOK;
#pragma unroll
  for (int tt = 0; tt < TT; ++tt) {
#pragma unroll
    for (int r = 0; r < 4; ++r) {
      float b = best[tt][r], s = sec[tt][r];
      int id = bct[tt][r] * 16 + row;   // code within chunk [0,1024)
#pragma unroll
      for (int w = 1; w < 16; w <<= 1) {
        const float ob = __shfl_xor(b, w, 64);
        const float os = __shfl_xor(s, w, 64);
        const int   oi = __shfl_xor(id, w, 64);
        s = fmaxf(fmaxf(s, os), fminf(b, ob));
        if (ob > b || (ob == b && oi < id)) id = oi;
        b = fmaxf(b, ob);
      }
      if (row == 0) {
        const int tok = (tile0 + tt) * 16 + grp * 4 + r;
        pbest[base + tok] = b;
        psec[base + tok] = s;
        pidx[base + tok] = (unsigned short)(chunk * 1024 + id);
      }
    }
  }
}

// merge 8 chunk-partials; per-token flag (no atomics) + per-block count
__global__ __launch_bounds__(BLK) void merge_kernel(
    const float* __restrict__ pbest, const float* __restrict__ psec,
    const unsigned short* __restrict__ pidx, int* __restrict__ fidx,
    unsigned* __restrict__ flags, int* __restrict__ bcount)
{
  const int t = blockIdx.x * BLK + threadIdx.x;
  float best = -3e38f, sec = -3e38f;
  int code = 0;
#pragma unroll
  for (int ch = 0; ch < NCHUNK; ++ch) {
    const float b = pbest[ch * N_TOK + t];
    const float s = psec[ch * N_TOK + t];
    const int c = pidx[ch * N_TOK + t];
    if (b > best) { sec = fmaxf(best, s); best = b; code = c; }
    else          { sec = fmaxf(sec, b); }
  }
  fidx[t] = code;
  const unsigned f = (best - sec < TAU) ? 1u : 0u;
  flags[t] = f;
  __shared__ int wcnt[4];
  const unsigned long long m = __ballot(f != 0);
  if ((threadIdx.x & 63) == 0) wcnt[threadIdx.x >> 6] = (int)__popcll(m);
  __syncthreads();
  if (threadIdx.x == 0)
    bcount[blockIdx.x] = wcnt[0] + wcnt[1] + wcnt[2] + wcnt[3];
}

// exclusive scan of 128 block counts (1 block, deterministic)
__global__ __launch_bounds__(128) void scan_kernel(
    const int* __restrict__ bcount, int* __restrict__ boff,
    int* __restrict__ nflagp)
{
  __shared__ int sh[128];
  const int tid = threadIdx.x;
  const int c = bcount[tid];
  sh[tid] = c;
  __syncthreads();
#pragma unroll
  for (int off = 1; off < 128; off <<= 1) {
    int v = 0;
    if (tid >= off) v = sh[tid - off];
    __syncthreads();
    sh[tid] += v;
    __syncthreads();
  }
  boff[tid] = sh[tid] - c;
  if (tid == 127) *nflagp = sh[127];
}

// deterministic compaction: flagged tokens in ascending order
__global__ __launch_bounds__(BLK) void scatter_kernel(
    const unsigned* __restrict__ flags, const int* __restrict__ boff,
    int* __restrict__ flaglist)
{
  const int tid = threadIdx.x;
  const int t = blockIdx.x * BLK + tid;
  const unsigned f = flags[t];
  const int lane = tid & 63, wv = tid >> 6;
  const unsigned long long m = __ballot(f != 0);
  __shared__ int wtot[4], woff[4];
  if (lane == 0) wtot[wv] = (int)__popcll(m);
  __syncthreads();
  if (tid == 0) {
    int s = 0;
#pragma unroll
    for (int w = 0; w < 4; ++w) { woff[w] = s; s += wtot[w]; }
  }
  __syncthreads();
  if (f) {
    const int rank = (int)__popcll(m & ((1ull << lane) - 1ull));
    flaglist[boff[blockIdx.x] + woff[wv] + rank] = t;
  }
}

// exact f64 rescan for flagged tokens, RG tokens per block (R7-proven body)
__global__ __launch_bounds__(256, 1) void recheck_kernel(
    const float* __restrict__ hs, const float* __restrict__ emb,
    const double* __restrict__ rza, const double* __restrict__ nsqa,
    const int* __restrict__ nflagp, const int* __restrict__ flaglist,
    int* __restrict__ fidx)
{
  __shared__ __align__(16) double zsh[RG][E_DIM];
  __shared__ int tsh[RG];
  __shared__ double rvW[RG][4];
  __shared__ int riW[RG][4];
  const int tid = threadIdx.x;
  const int lane = tid & 63, wv = tid >> 6;
  const int nflag = *nflagp;
  for (int base = blockIdx.x * RG; base < nflag; base += gridDim.x * RG) {
    __syncthreads();
    if (tid < 128) {
      const int g = tid >> 5, j = tid & 31;
      const bool act = (base + g) < nflag;
      const int t = act ? flaglist[base + g] : -1;
      if (j == 0) tsh[g] = t;
      const double zj = act ? (double)hs[t * E_DIM + j] : 0.0;
      double sq = zj * zj;
#pragma unroll
      for (int o = 16; o > 0; o >>= 1) sq += __shfl_xor(sq, o, 32);
      const double rzt = 1.0 / sqrt(sq + 1e-12);
      zsh[g][j] = zj * rzt;
    }
    __syncthreads();

    double bobj[RG];
    int bidx[RG];
#pragma unroll
    for (int g = 0; g < RG; ++g) { bobj[g] = 1e300; bidx[g] = 0x7fffffff; }

    for (int c = tid; c < K_CODES; c += 256) {
      const float4* ep = (const float4*)(emb + c * E_DIM);
      f64x4 e64[8];
#pragma unroll
      for (int q = 0; q < 8; ++q) {
        const float4 v = ep[q];
        e64[q][0] = (double)v.x; e64[q][1] = (double)v.y;
        e64[q][2] = (double)v.z; e64[q][3] = (double)v.w;
      }
      const double rzc = rza[c], nsqc = nsqa[c];
#pragma unroll
      for (int g = 0; g < RG; ++g) {
        double d0 = 0.0, d1 = 0.0;
#pragma unroll
        for (int q = 0; q < 8; q += 2) {
#pragma unroll
          for (int x = 0; x < 4; ++x) {
            d0 = fma(e64[q][x],     zsh[g][q * 4 + x],       d0);
            d1 = fma(e64[q + 1][x], zsh[g][(q + 1) * 4 + x], d1);
          }
        }
        const double obj = fma(-2.0, (d0 + d1) * rzc, nsqc);
        if (obj < bobj[g]) { bobj[g] = obj; bidx[g] = c; }
      }
    }

#pragma unroll
    for (int g = 0; g < RG; ++g) {
      double b = bobj[g]; int i = bidx[g];
#pragma unroll
      for (int o = 32; o > 0; o >>= 1) {
        const double ob = __shfl_down(b, o, 64);
        const int oi = __shfl_down(i, o, 64);
        if (ob < b || (ob == b && oi < i)) { b = ob; i = oi; }
      }
      if (lane == 0) { rvW[g][wv] = b; riW[g][wv] = i; }
    }
    __syncthreads();
    if (tid < RG) {
      const int g = tid;
      double b = rvW[g][0]; int i = riW[g][0];
#pragma unroll
      for (int w = 1; w < 4; ++w) {
        const double ob = rvW[g][w]; const int oi = riW[g][w];
        if (ob < b || (ob == b && oi < i)) { b = ob; i = oi; }
      }
      const int t = tsh[g];
      if (t >= 0) fidx[t] = i;
    }
  }
}

__global__ __launch_bounds__(BLK) void finalize_kernel(
    const float* __restrict__ hs, const float* __restrict__ emb,
    const int* __restrict__ fidx, float* __restrict__ out,
    float* __restrict__ lpart)
{
  const int t = blockIdx.x * BLK + threadIdx.x;
  const int idx = fidx[t];
  const float4* ep = (const float4*)(emb + idx * E_DIM);
  const float4* hp = (const float4*)(hs + t * E_DIM);
  float4 e[8], h[8];
  float se = 0.f, sh = 0.f;
#pragma unroll
  for (int q = 0; q < 8; ++q) {
    e[q] = ep[q]; h[q] = hp[q];
    se += e[q].x * e[q].x + e[q].y * e[q].y + e[q].z * e[q].z + e[q].w * e[q].w;
    sh += h[q].x * h[q].x + h[q].y * h[q].y + h[q].z * h[q].z + h[q].w * h[q].w;
  }
  const float re = 1.f / sqrtf(se + 1e-12f);
  const float rh = 1.f / sqrtf(sh + 1e-12f);
  float4* zo = (float4*)(out + t * E_DIM);
  float err = 0.f;
#pragma unroll
  for (int q = 0; q < 8; ++q) {
    float4 zq, hn;
    zq.x = e[q].x * re; zq.y = e[q].y * re; zq.z = e[q].z * re; zq.w = e[q].w * re;
    hn.x = h[q].x * rh; hn.y = h[q].y * rh; hn.z = h[q].z * rh; hn.w = h[q].w * rh;
    float dx = zq.x - hn.x, dy = zq.y - hn.y, dz = zq.z - hn.z, dw = zq.w - hn.w;
    err += dx * dx + dy * dy + dz * dz + dw * dw;
    zo[q] = zq;
  }
  out[OUT_IDX + t] = (float)idx;
#pragma unroll
  for (int o = 32; o > 0; o >>= 1) err += __shfl_down(err, o);
  if ((threadIdx.x & 63) == 0) lpart[t >> 6] = err;
}

__global__ __launch_bounds__(256) void loss_kernel(
    const float* __restrict__ lpart, float* __restrict__ out)
{
  const int tid = threadIdx.x;
  float a = lpart[tid] + lpart[tid + 256];
#pragma unroll
  for (int o = 32; o > 0; o >>= 1) a += __shfl_down(a, o);
  __shared__ float w[4];
  if ((tid & 63) == 0) w[tid >> 6] = a;
  __syncthreads();
  if (tid == 0) {
    const float tot = (w[0] + w[1]) + (w[2] + w[3]);
    const float c = tot * (1.0f / 1048576.0f);
    out[OUT_QL] = c;
    out[OUT_EL] = c;
  }
}

extern "C" void kernel_launch(void* const* d_in, const int* in_sizes, int n_in,
                              void* d_out, int out_size, void* d_ws, size_t ws_size,
                              hipStream_t stream) {
  (void)in_sizes; (void)n_in; (void)out_size; (void)ws_size;
  const float* hs  = (const float*)d_in[0];
  const float* emb = (const float*)d_in[1];
  float* out = (float*)d_out;
  char* wsb = (char*)d_ws;

  char*           Bpk   = wsb + WSB_BPK;
  float*          pbest = (float*)(wsb + WSB_PBEST);
  float*          psec  = (float*)(wsb + WSB_PSEC);
  unsigned short* pidx  = (unsigned short*)(wsb + WSB_PIDX);
  int*            fidx  = (int*)(wsb + WSB_FIDX);
  float*          lpart = (float*)(wsb + WSB_LPART);
  double*         rza   = (double*)(wsb + WSB_PBEST);          // overlay, after merge
  double*         nsqa  = (double*)(wsb + WSB_PBEST + 65536);
  // out z_q region as pre-finalize scratch (fully overwritten by finalize)
  unsigned*       flags   = (unsigned*)(out + OUTS_FLAGS);
  int*            flist   = (int*)(out + OUTS_FLIST);
  int*            bcount  = (int*)(out + OUTS_BCNT);
  int*            boff    = (int*)(out + OUTS_BOFF);
  int*            nflagp  = (int*)(out + OUTS_NFLAG);

  prep_emb_kernel<<<dim3(K_CODES / BLK), BLK, 0, stream>>>(emb, Bpk);
  screen_kernel<<<dim3(NCHUNK * 128), BLK, 0, stream>>>(hs, Bpk, pbest, psec, pidx);
  merge_kernel<<<dim3(N_TOK / BLK), BLK, 0, stream>>>(pbest, psec, pidx, fidx, flags, bcount);
  scan_kernel<<<dim3(1), 128, 0, stream>>>(bcount, boff, nflagp);
  scatter_kernel<<<dim3(N_TOK / BLK), BLK, 0, stream>>>(flags, boff, flist);
  prep64_kernel<<<dim3(K_CODES / 256), 256, 0, stream>>>(emb, rza, nsqa);
  recheck_kernel<<<dim3(512), 256, 0, stream>>>(hs, emb, rza, nsqa, nflagp, flist, fidx);
  finalize_kernel<<<dim3(N_TOK / BLK), BLK, 0, stream>>>(hs, emb, fidx, out, lpart);
  loss_kernel<<<dim3(1), 256, 0, stream>>>(lpart, out);
}